// Round 1
// baseline (325.643 us; speedup 1.0000x reference)
//
#include <hip/hip_runtime.h>

// GaussianSplatting preprocess:
//   out = concat(positions [N,3], cov [N,3,3], alphas [N], sh [N,4]) flat f32
//   cov = R (S S^T) R^T = (R S)(R S)^T
//   sh  = [SH_C0, c1*SH_C1, c0*SH_C1, c2*SH_C1]
// Memory-bound streaming: ~200 MB in, ~136 MB out, ~53 us/dispatch floor @ 6.3 TB/s.
//
// v2: 4 points per thread so every global access is an aligned float4:
//   R/S/cov: 4 pts * 9 f = 36 f = 9 float4   (vs 9 unaligned scalar dwords)
//   pos/col: 4 pts * 3 f = 12 f = 3 float4
//   alp:     4 pts       =  4 f = 1 float4
//   sh:      4 pts * 4 f = 16 f = 4 float4
// dwordx4 everywhere -> 4x bytes per VMEM instruction in flight.

#define SH_C0 0.282095f
#define SH_C1 0.488603f

__global__ __launch_bounds__(256) void gs_kernel_v4(
    const float4* __restrict__ pos4,   // [nv*3]
    const float4* __restrict__ col4,   // [nv*3]
    const float4* __restrict__ alp4,   // [nv]
    const float4* __restrict__ R4,     // [nv*9]
    const float4* __restrict__ S4,     // [nv*9]
    float4* __restrict__ out_pos4,     // [nv*3]
    float4* __restrict__ out_cov4,     // [nv*9]
    float4* __restrict__ out_alp4,     // [nv]
    float4* __restrict__ out_sh4,      // [nv*4]
    int nv)                            // n/4
{
    int j = blockIdx.x * blockDim.x + threadIdx.x;
    if (j >= nv) return;

    // --- positions passthrough: 3 aligned float4 ---
#pragma unroll
    for (int k = 0; k < 3; ++k) out_pos4[3 * j + k] = pos4[3 * j + k];

    // --- alphas passthrough: 1 aligned float4 ---
    out_alp4[j] = alp4[j];

    // --- sh coeffs: 12 colors in (3 float4), 16 sh out (4 float4) ---
    {
        float c[12];
#pragma unroll
        for (int k = 0; k < 3; ++k) {
            float4 v = col4[3 * j + k];
            c[4 * k + 0] = v.x; c[4 * k + 1] = v.y;
            c[4 * k + 2] = v.z; c[4 * k + 3] = v.w;
        }
#pragma unroll
        for (int p = 0; p < 4; ++p) {
            out_sh4[4 * j + p] = make_float4(SH_C0,
                                             c[3 * p + 1] * SH_C1,
                                             c[3 * p + 0] * SH_C1,
                                             c[3 * p + 2] * SH_C1);
        }
    }

    // --- cov = (R S)(R S)^T for 4 points: 9+9 float4 in, 9 float4 out ---
    float r[36], s[36];
#pragma unroll
    for (int k = 0; k < 9; ++k) {
        float4 v = R4[9 * j + k];
        r[4 * k + 0] = v.x; r[4 * k + 1] = v.y;
        r[4 * k + 2] = v.z; r[4 * k + 3] = v.w;
    }
#pragma unroll
    for (int k = 0; k < 9; ++k) {
        float4 v = S4[9 * j + k];
        s[4 * k + 0] = v.x; s[4 * k + 1] = v.y;
        s[4 * k + 2] = v.z; s[4 * k + 3] = v.w;
    }

#pragma unroll
    for (int p = 0; p < 4; ++p) {
        const int o = 9 * p;
        float t[9];  // T = R_p @ S_p (row-major 3x3)
#pragma unroll
        for (int a = 0; a < 3; ++a) {
#pragma unroll
            for (int b = 0; b < 3; ++b) {
                t[3 * a + b] = r[o + 3 * a + 0] * s[o + 0 + b]
                             + r[o + 3 * a + 1] * s[o + 3 + b]
                             + r[o + 3 * a + 2] * s[o + 6 + b];
            }
        }
        // S_p fully consumed -> overwrite with cov_p in place (caps live VGPRs)
#pragma unroll
        for (int a = 0; a < 3; ++a) {
#pragma unroll
            for (int b = 0; b < 3; ++b) {
                s[o + 3 * a + b] = t[3 * a + 0] * t[3 * b + 0]
                                 + t[3 * a + 1] * t[3 * b + 1]
                                 + t[3 * a + 2] * t[3 * b + 2];
            }
        }
    }

#pragma unroll
    for (int k = 0; k < 9; ++k) {
        out_cov4[9 * j + k] = make_float4(s[4 * k + 0], s[4 * k + 1],
                                          s[4 * k + 2], s[4 * k + 3]);
    }
}

// Scalar fallback for the (n % 4) tail — identical math to v1.
__global__ __launch_bounds__(64) void gs_kernel_tail(
    const float* __restrict__ pos,
    const float* __restrict__ col,
    const float* __restrict__ alp,
    const float* __restrict__ Rm,
    const float* __restrict__ Sm,
    float* __restrict__ out_pos,
    float* __restrict__ out_cov,
    float* __restrict__ out_alp,
    float* __restrict__ out_sh,
    int base, int n)
{
    int i = base + threadIdx.x;
    if (i >= n) return;

    out_pos[3 * i + 0] = pos[3 * i + 0];
    out_pos[3 * i + 1] = pos[3 * i + 1];
    out_pos[3 * i + 2] = pos[3 * i + 2];
    out_alp[i] = alp[i];

    float c0 = col[3 * i + 0];
    float c1 = col[3 * i + 1];
    float c2 = col[3 * i + 2];
    out_sh[4 * i + 0] = SH_C0;
    out_sh[4 * i + 1] = c1 * SH_C1;
    out_sh[4 * i + 2] = c0 * SH_C1;
    out_sh[4 * i + 3] = c2 * SH_C1;

    float r[9], s[9];
#pragma unroll
    for (int k = 0; k < 9; ++k) r[k] = Rm[9 * i + k];
#pragma unroll
    for (int k = 0; k < 9; ++k) s[k] = Sm[9 * i + k];

    float t[9];
#pragma unroll
    for (int a = 0; a < 3; ++a)
#pragma unroll
        for (int b = 0; b < 3; ++b)
            t[3 * a + b] = r[3 * a + 0] * s[0 + b]
                         + r[3 * a + 1] * s[3 + b]
                         + r[3 * a + 2] * s[6 + b];

#pragma unroll
    for (int a = 0; a < 3; ++a)
#pragma unroll
        for (int b = 0; b < 3; ++b)
            out_cov[9 * i + 3 * a + b] = t[3 * a + 0] * t[3 * b + 0]
                                       + t[3 * a + 1] * t[3 * b + 1]
                                       + t[3 * a + 2] * t[3 * b + 2];
}

extern "C" void kernel_launch(void* const* d_in, const int* in_sizes, int n_in,
                              void* d_out, int out_size, void* d_ws, size_t ws_size,
                              hipStream_t stream) {
    const float* pos = (const float*)d_in[0];  // [N,3]
    const float* col = (const float*)d_in[1];  // [N,3]
    const float* alp = (const float*)d_in[2];  // [N]
    const float* Rm  = (const float*)d_in[3];  // [N,3,3]
    const float* Sm  = (const float*)d_in[4];  // [N,3,3]

    int n = in_sizes[0] / 3;

    float* out = (float*)d_out;
    float* out_pos = out;             // n*3
    float* out_cov = out + 3 * n;     // n*9
    float* out_alp = out + 12 * n;    // n
    float* out_sh  = out + 13 * n;    // n*4

    int nv = n / 4;          // fully-vectorized 4-point groups
    int rem_base = nv * 4;   // scalar tail (0 for N=2M)

    if (nv > 0) {
        int block = 256;
        int grid = (nv + block - 1) / block;
        gs_kernel_v4<<<grid, block, 0, stream>>>(
            (const float4*)pos, (const float4*)col, (const float4*)alp,
            (const float4*)Rm, (const float4*)Sm,
            (float4*)out_pos, (float4*)out_cov, (float4*)out_alp, (float4*)out_sh,
            nv);
    }
    if (rem_base < n) {
        gs_kernel_tail<<<1, 64, 0, stream>>>(pos, col, alp, Rm, Sm,
                                             out_pos, out_cov, out_alp, out_sh,
                                             rem_base, n);
    }
}

// Round 2
// 295.475 us; speedup vs baseline: 1.1021x; 1.1021x over previous
//
#include <hip/hip_runtime.h>

// GaussianSplatting preprocess:
//   out = concat(positions [N,3], cov [N,3,3], alphas [N], sh [N,4]) flat f32
//   cov = R (S S^T) R^T = (R S)(R S)^T   (algebraic simplification, fewer FLOPs)
//   sh  = [SH_C0, c1*SH_C1, c0*SH_C1, c2*SH_C1]
//
// v3 = v1 (best measured: 95 us/dispatch, dense 36B-stride scalar access) +
//      NON-TEMPORAL stores for all outputs.
// Rationale (from R1 counters): input (200 MB) + output (136 MB) > 256 MB L3,
// so cached output writes evict input every iteration (FETCH was ~98 MB).
// Output is never re-read -> nt stores keep L3 input-resident; HBM traffic
// drops toward the compulsory 136 MB of writes.
// (R1 lesson: float4/144B-stride layout amplified traffic 1.4x — partial-line
// scatter at the L2/HBM boundary. Dense scalar 36B stride is line-optimal.)

#define SH_C0 0.282095f
#define SH_C1 0.488603f

__global__ __launch_bounds__(256) void gs_kernel(
    const float* __restrict__ pos,
    const float* __restrict__ col,
    const float* __restrict__ alp,
    const float* __restrict__ Rm,
    const float* __restrict__ Sm,
    float* __restrict__ out_pos,   // [n*3]
    float* __restrict__ out_cov,   // [n*9]
    float* __restrict__ out_alp,   // [n]
    float* __restrict__ out_sh,    // [n*4]
    int n)
{
    int i = blockIdx.x * blockDim.x + threadIdx.x;
    if (i >= n) return;

    // --- positions passthrough ---
    __builtin_nontemporal_store(pos[3 * i + 0], &out_pos[3 * i + 0]);
    __builtin_nontemporal_store(pos[3 * i + 1], &out_pos[3 * i + 1]);
    __builtin_nontemporal_store(pos[3 * i + 2], &out_pos[3 * i + 2]);

    // --- alphas passthrough ---
    __builtin_nontemporal_store(alp[i], &out_alp[i]);

    // --- sh coeffs ---
    float c0 = col[3 * i + 0];
    float c1 = col[3 * i + 1];
    float c2 = col[3 * i + 2];
    __builtin_nontemporal_store(SH_C0,        &out_sh[4 * i + 0]);
    __builtin_nontemporal_store(c1 * SH_C1,   &out_sh[4 * i + 1]);
    __builtin_nontemporal_store(c0 * SH_C1,   &out_sh[4 * i + 2]);
    __builtin_nontemporal_store(c2 * SH_C1,   &out_sh[4 * i + 3]);

    // --- cov = (R S)(R S)^T ---
    float r[9], s[9];
#pragma unroll
    for (int k = 0; k < 9; ++k) r[k] = Rm[9 * i + k];
#pragma unroll
    for (int k = 0; k < 9; ++k) s[k] = Sm[9 * i + k];

    float t[9];  // T = R @ S  (row-major 3x3)
#pragma unroll
    for (int a = 0; a < 3; ++a) {
#pragma unroll
        for (int b = 0; b < 3; ++b) {
            t[3 * a + b] = r[3 * a + 0] * s[0 + b]
                         + r[3 * a + 1] * s[3 + b]
                         + r[3 * a + 2] * s[6 + b];
        }
    }

#pragma unroll
    for (int a = 0; a < 3; ++a) {
#pragma unroll
        for (int b = 0; b < 3; ++b) {
            float v = t[3 * a + 0] * t[3 * b + 0]
                    + t[3 * a + 1] * t[3 * b + 1]
                    + t[3 * a + 2] * t[3 * b + 2];
            __builtin_nontemporal_store(v, &out_cov[9 * i + 3 * a + b]);
        }
    }
}

extern "C" void kernel_launch(void* const* d_in, const int* in_sizes, int n_in,
                              void* d_out, int out_size, void* d_ws, size_t ws_size,
                              hipStream_t stream) {
    const float* pos = (const float*)d_in[0];  // [N,3]
    const float* col = (const float*)d_in[1];  // [N,3]
    const float* alp = (const float*)d_in[2];  // [N]
    const float* Rm  = (const float*)d_in[3];  // [N,3,3]
    const float* Sm  = (const float*)d_in[4];  // [N,3,3]

    int n = in_sizes[0] / 3;

    float* out = (float*)d_out;
    float* out_pos = out;             // n*3
    float* out_cov = out + 3 * n;     // n*9
    float* out_alp = out + 12 * n;    // n
    float* out_sh  = out + 13 * n;    // n*4

    int block = 256;
    int grid = (n + block - 1) / block;
    gs_kernel<<<grid, block, 0, stream>>>(pos, col, alp, Rm, Sm,
                                          out_pos, out_cov, out_alp, out_sh, n);
}

// Round 4
// 281.735 us; speedup vs baseline: 1.1558x; 1.0488x over previous
//
#include <hip/hip_runtime.h>

// GaussianSplatting preprocess:
//   out = concat(positions [N,3], cov [N,3,3], alphas [N], sh [N,4]) flat f32
//   cov = R (S S^T) R^T = (R S)(R S)^T
//   sh  = [SH_C0, c1*SH_C1, c0*SH_C1, c2*SH_C1]
//
// v4b: LDS-staged coalescing (resubmit of v4 — R3 bench died to container
// infra failure, no counters; kernel audited sound: 30KB LDS, aligned float4,
// block-uniform barriers).
// Evidence (R0-R2): v1 scalar (236 MB), float4/144B-stride (336 MB), v1+nt
// (278 MB) ALL ran at the same ~2.45 TB/s of hbm_bytes/dur -> transaction-path
// saturation, not HBM BW. Cause: 36B/lane record stride => each wave64 dword
// load spans 18 lines partially, re-touched 9x, L1 (32KB) evicts between
// touches => ~8x L1-miss transaction amplification, MSHR-occupancy bound.
// Fix: block-cooperative float4 staging of R/S/col through LDS + coalesced
// float4 pos/alp passthrough + coalesced cov store via LDS. Every global
// instruction covers 8 full unique cache lines exactly once.
// (nt stores reverted: R2 showed +30% WRITE_SIZE from partial-line evicts.)

#define SH_C0 0.282095f
#define SH_C1 0.488603f
#define BLK 256

__global__ __launch_bounds__(BLK) void gs_kernel(
    const float* __restrict__ pos,
    const float* __restrict__ col,
    const float* __restrict__ alp,
    const float* __restrict__ Rm,
    const float* __restrict__ Sm,
    float* __restrict__ out_pos,   // [n*3]
    float* __restrict__ out_cov,   // [n*9]
    float* __restrict__ out_alp,   // [n]
    float* __restrict__ out_sh,    // [n*4]
    int n)
{
    // 256 points/block: R,S,cov = 576 float4 (9 KB) each, col = 192 float4 (3 KB)
    __shared__ float4 ldsR4[576];
    __shared__ float4 ldsS4[576];
    __shared__ float4 ldsC4[576];   // cov out-staging
    __shared__ float4 ldsCol4[192];

    const int t = threadIdx.x;
    const int base = blockIdx.x * BLK;  // first point of this block

    if (base + BLK <= n) {
        // ---------------- full-block fast path ----------------
        const float4* R4 = (const float4*)(Rm  + (size_t)base * 9);
        const float4* S4 = (const float4*)(Sm  + (size_t)base * 9);
        const float4* C4 = (const float4*)(col + (size_t)base * 3);
        const float4* P4 = (const float4*)(pos + (size_t)base * 3);
        const float4* A4 = (const float4*)(alp + (size_t)base);
        float4* OP4 = (float4*)(out_pos + (size_t)base * 3);
        float4* OA4 = (float4*)(out_alp + (size_t)base);
        float4* OS4 = (float4*)(out_sh  + (size_t)base * 4);
        float4* OC4 = (float4*)(out_cov + (size_t)base * 9);

        // stage inputs (each wave64 float4 instr = 1024 B = 8 full lines)
        ldsR4[t]       = R4[t];
        ldsR4[t + 256] = R4[t + 256];
        ldsS4[t]       = S4[t];
        ldsS4[t + 256] = S4[t + 256];
        if (t < 64) {
            ldsR4[t + 512] = R4[t + 512];
            ldsS4[t + 512] = S4[t + 512];
            OA4[t] = A4[t];          // alphas passthrough, coalesced
        }
        if (t < 192) {
            ldsCol4[t] = C4[t];
            OP4[t] = P4[t];          // positions passthrough, coalesced
        }

        __syncthreads();

        // per-thread compute from LDS (stride-9 floats -> 2-way bank alias = free)
        const float* rf = (const float*)ldsR4 + t * 9;
        const float* sf = (const float*)ldsS4 + t * 9;
        float r[9], s[9];
#pragma unroll
        for (int k = 0; k < 9; ++k) r[k] = rf[k];
#pragma unroll
        for (int k = 0; k < 9; ++k) s[k] = sf[k];

        float tm[9];  // T = R @ S
#pragma unroll
        for (int a = 0; a < 3; ++a)
#pragma unroll
            for (int b = 0; b < 3; ++b)
                tm[3 * a + b] = r[3 * a + 0] * s[0 + b]
                              + r[3 * a + 1] * s[3 + b]
                              + r[3 * a + 2] * s[6 + b];

        float* cf = (float*)ldsC4 + t * 9;
#pragma unroll
        for (int a = 0; a < 3; ++a)
#pragma unroll
            for (int b = 0; b < 3; ++b)
                cf[3 * a + b] = tm[3 * a + 0] * tm[3 * b + 0]
                              + tm[3 * a + 1] * tm[3 * b + 1]
                              + tm[3 * a + 2] * tm[3 * b + 2];

        // sh: one float4 per point -> naturally coalesced direct store
        const float* cc = (const float*)ldsCol4 + t * 3;
        OS4[t] = make_float4(SH_C0, cc[1] * SH_C1, cc[0] * SH_C1, cc[2] * SH_C1);

        __syncthreads();

        // cov: cooperative coalesced float4 store
        OC4[t]       = ldsC4[t];
        OC4[t + 256] = ldsC4[t + 256];
        if (t < 64) OC4[t + 512] = ldsC4[t + 512];
    } else {
        // ---------------- guarded scalar tail ----------------
        int i = base + t;
        if (i >= n) return;

        out_pos[3 * i + 0] = pos[3 * i + 0];
        out_pos[3 * i + 1] = pos[3 * i + 1];
        out_pos[3 * i + 2] = pos[3 * i + 2];
        out_alp[i] = alp[i];

        float c0 = col[3 * i + 0];
        float c1 = col[3 * i + 1];
        float c2 = col[3 * i + 2];
        out_sh[4 * i + 0] = SH_C0;
        out_sh[4 * i + 1] = c1 * SH_C1;
        out_sh[4 * i + 2] = c0 * SH_C1;
        out_sh[4 * i + 3] = c2 * SH_C1;

        float r[9], s[9];
#pragma unroll
        for (int k = 0; k < 9; ++k) r[k] = Rm[9 * i + k];
#pragma unroll
        for (int k = 0; k < 9; ++k) s[k] = Sm[9 * i + k];

        float tm[9];
#pragma unroll
        for (int a = 0; a < 3; ++a)
#pragma unroll
            for (int b = 0; b < 3; ++b)
                tm[3 * a + b] = r[3 * a + 0] * s[0 + b]
                              + r[3 * a + 1] * s[3 + b]
                              + r[3 * a + 2] * s[6 + b];

#pragma unroll
        for (int a = 0; a < 3; ++a)
#pragma unroll
            for (int b = 0; b < 3; ++b)
                out_cov[9 * i + 3 * a + b] = tm[3 * a + 0] * tm[3 * b + 0]
                                           + tm[3 * a + 1] * tm[3 * b + 1]
                                           + tm[3 * a + 2] * tm[3 * b + 2];
    }
}

extern "C" void kernel_launch(void* const* d_in, const int* in_sizes, int n_in,
                              void* d_out, int out_size, void* d_ws, size_t ws_size,
                              hipStream_t stream) {
    const float* pos = (const float*)d_in[0];  // [N,3]
    const float* col = (const float*)d_in[1];  // [N,3]
    const float* alp = (const float*)d_in[2];  // [N]
    const float* Rm  = (const float*)d_in[3];  // [N,3,3]
    const float* Sm  = (const float*)d_in[4];  // [N,3,3]

    int n = in_sizes[0] / 3;

    float* out = (float*)d_out;
    float* out_pos = out;             // n*3
    float* out_cov = out + 3 * n;     // n*9
    float* out_alp = out + 12 * n;    // n
    float* out_sh  = out + 13 * n;    // n*4

    int block = BLK;
    int grid = (n + block - 1) / block;
    gs_kernel<<<grid, block, 0, stream>>>(pos, col, alp, Rm, Sm,
                                          out_pos, out_cov, out_alp, out_sh, n);
}